// Round 1
// 5709.593 us; speedup vs baseline: 1.0831x; 1.0831x over previous
//
#include <hip/hip_runtime.h>
#include <hip/hip_bf16.h>

// GPT-style transformer forward, MI355X/gfx950.
// Round 1: m97-structure GEMM (global_load_lds width=16, linear LDS),
//          causal block-skip (S) + K-truncation (PV), nontemporal logits
//          stores, XCD swizzle on the head GEMM.

#define NBATCH 4
#define TT 1024
#define DD 768
#define NH 12
#define HK 64
#define NL 6
#define NV 32000
#define BT 4096      // NBATCH*TT
#define HD 9216      // NH*DD
#define FF 3072      // 4*DD

using bf16x8 = __attribute__((ext_vector_type(8))) short;
using f32x4  = __attribute__((ext_vector_type(4))) float;

#define GF_OUTBF16 1
#define GF_ACCUM   2
#define GF_BIAS    4
#define GF_RELU    8
#define GF_CAUSAL  16   // skip tiles strictly above the diagonal (S = Q K^T)
#define GF_KTRUNC  32   // K-loop only to m0+128 (PV with causal P)
#define GF_SWIZZLE 64   // bijective XCD-aware block remap (L2 locality)

// ---------------------------------------------------------------- GEMM
// C[m,n] = sum_k A[m,k] * Bt[n,k]   (both bf16, row-major, fp32 accumulate)
// Tile: 128x128, BK=32. Block 256 thr = 4 waves, each wave 64x64 via 4x4 MFMAs.
// Staging: global_load_lds dwordx4 (m97 structure), linear LDS [128][32].
// Batched: offset = (g/GH)*s1 + (g%GH)*s2 for A, Bt, C (element strides).
__global__ __launch_bounds__(256, 2)
void gemm_kernel(const __hip_bfloat16* __restrict__ A,
                 const __hip_bfloat16* __restrict__ Bt,
                 void* __restrict__ Cv,
                 const float* __restrict__ bias,
                 int Kd, int lda, int ldb, int ldc,
                 int GH,
                 long sA1, long sA2, long sB1, long sB2, long sC1, long sC2,
                 int flags, float scale)
{
    int bx = blockIdx.x, by = blockIdx.y;
    if (flags & GF_SWIZZLE) {
        int gx = gridDim.x, gy = gridDim.y;
        int nwg = gx * gy;
        int id  = by * gx + bx;
        int q = nwg >> 3, r = nwg & 7;
        int xcd = id & 7, loc = id >> 3;
        int sw = (xcd < r) ? xcd * (q + 1) + loc
                           : r * (q + 1) + (xcd - r) * q + loc;
        bx = sw % gx;
        by = sw / gx;
    }
    int n0 = bx * 128, m0 = by * 128;
    if ((flags & GF_CAUSAL) && n0 > m0) return;   // fully-masked tile
    int Keff = (flags & GF_KTRUNC) ? ((Kd < m0 + 128) ? Kd : m0 + 128) : Kd;

    int g  = blockIdx.z;
    int g1 = g / GH, g2 = g % GH;
    const short* Ag = (const short*)A  + g1 * sA1 + g2 * sA2;
    const short* Bg = (const short*)Bt + g1 * sB1 + g2 * sB2;
    long coff = g1 * sC1 + g2 * sC2;

    __shared__ short As[128 * 32];   // linear: required by global_load_lds
    __shared__ short Bs[128 * 32];

    int tid  = threadIdx.x;
    int wave = tid >> 6, lane = tid & 63;
    int wm = (wave >> 1) * 64, wn = (wave & 1) * 64;
    int lm = lane & 15, quad = lane >> 4;
    int srow = lane >> 2;            // 0..15 within a 16-row chunk
    int scol = (lane & 3) << 3;      // 0,8,16,24 (bf16 elems)

    f32x4 acc[4][4];
#pragma unroll
    for (int i = 0; i < 4; i++)
#pragma unroll
        for (int j = 0; j < 4; j++) acc[i][j] = (f32x4){0.f, 0.f, 0.f, 0.f};

    for (int k0 = 0; k0 < Keff; k0 += 32) {
        __syncthreads();
        // 8 chunks of 16 rows each per matrix; wave w stages chunks {w, w+4}.
        // LDS dest is wave-uniform base + lane*16B (linear), global src per-lane.
#pragma unroll
        for (int i = 0; i < 2; i++) {
            int c   = wave + (i << 2);           // chunk 0..7
            int row = (c << 4) + srow;
            __builtin_amdgcn_global_load_lds(
                (const __attribute__((address_space(1))) void*)
                    (Ag + (long)(m0 + row) * lda + k0 + scol),
                (__attribute__((address_space(3))) void*)
                    (&As[(c << 9) + (lane << 3)]),
                16, 0, 0);
            __builtin_amdgcn_global_load_lds(
                (const __attribute__((address_space(1))) void*)
                    (Bg + (long)(n0 + row) * ldb + k0 + scol),
                (__attribute__((address_space(3))) void*)
                    (&Bs[(c << 9) + (lane << 3)]),
                16, 0, 0);
        }
        __syncthreads();

        bf16x8 af[4], bfv[4];
#pragma unroll
        for (int mi = 0; mi < 4; mi++)
            af[mi] = *(const bf16x8*)(&As[(wm + mi * 16 + lm) * 32 + quad * 8]);
#pragma unroll
        for (int ni = 0; ni < 4; ni++)
            bfv[ni] = *(const bf16x8*)(&Bs[(wn + ni * 16 + lm) * 32 + quad * 8]);
#pragma unroll
        for (int mi = 0; mi < 4; mi++)
#pragma unroll
            for (int ni = 0; ni < 4; ni++)
                acc[mi][ni] = __builtin_amdgcn_mfma_f32_16x16x32_bf16(
                    af[mi], bfv[ni], acc[mi][ni], 0, 0, 0);
    }

    bool outbf = flags & GF_OUTBF16;
    bool accum = flags & GF_ACCUM;
    bool hbias = flags & GF_BIAS;
    bool relu  = flags & GF_RELU;
#pragma unroll
    for (int mi = 0; mi < 4; mi++) {
#pragma unroll
        for (int ni = 0; ni < 4; ni++) {
            int colg = n0 + wn + ni * 16 + lm;
            float bv = hbias ? bias[colg] : 0.f;
#pragma unroll
            for (int r = 0; r < 4; r++) {
                int rowg = m0 + wm + mi * 16 + quad * 4 + r;
                float v = acc[mi][ni][r] * scale + bv;
                if (relu) v = fmaxf(v, 0.f);
                long idx = coff + (long)rowg * ldc + colg;
                if (outbf) {
                    ((__hip_bfloat16*)Cv)[idx] = __float2bfloat16(v);
                } else if (accum) {
                    float* cp = (float*)Cv + idx;
                    *cp = *cp + v;
                } else {
                    // streaming f32 output (logits): don't pollute L2/L3,
                    // keep the Whead B-panel cache-resident.
                    __builtin_nontemporal_store(v, (float*)Cv + idx);
                }
            }
        }
    }
}

// ------------------------------------------------- weight transpose f32->bf16
// in: (R x C) f32 row-major; out: (C x R) bf16 row-major. Dims multiple of 32.
__global__ void transpose_kernel(const float* __restrict__ in,
                                 __hip_bfloat16* __restrict__ out,
                                 int R, int C, long inBatch, long outBatch)
{
    __shared__ float tile[32][33];
    long ib = (long)blockIdx.z * inBatch;
    long ob = (long)blockIdx.z * outBatch;
    int c0 = blockIdx.x * 32, r0 = blockIdx.y * 32;
    int tx = threadIdx.x, ty = threadIdx.y;   // 32 x 8
#pragma unroll
    for (int i = 0; i < 4; i++) {
        int r = r0 + ty + i * 8;
        tile[ty + i * 8][tx] = in[ib + (long)r * C + c0 + tx];
    }
    __syncthreads();
#pragma unroll
    for (int i = 0; i < 4; i++) {
        int c = c0 + ty + i * 8;
        out[ob + (long)c * R + r0 + tx] = __float2bfloat16(tile[tx][ty + i * 8]);
    }
}

// ---------------------------------------------------------------- LayerNorm
// one block (256 thr) per row of 768; writes bf16
__global__ void ln_kernel(const float* __restrict__ x,
                          const float* __restrict__ g,
                          const float* __restrict__ b,
                          __hip_bfloat16* __restrict__ out)
{
    int row = blockIdx.x;
    const float* xp = x + (long)row * DD;
    int tid = threadIdx.x;
    float a0 = xp[tid], a1 = xp[tid + 256], a2 = xp[tid + 512];
    float s = a0 + a1 + a2;
    for (int off = 32; off; off >>= 1) s += __shfl_down(s, off);
    __shared__ float red[4];
    int wave = tid >> 6, lane = tid & 63;
    if (lane == 0) red[wave] = s;
    __syncthreads();
    float mean = (red[0] + red[1] + red[2] + red[3]) * (1.f / DD);
    float d0 = a0 - mean, d1 = a1 - mean, d2 = a2 - mean;
    float vs = d0 * d0 + d1 * d1 + d2 * d2;
    for (int off = 32; off; off >>= 1) vs += __shfl_down(vs, off);
    __syncthreads();
    if (lane == 0) red[wave] = vs;
    __syncthreads();
    float var  = (red[0] + red[1] + red[2] + red[3]) * (1.f / DD);
    float rstd = rsqrtf(var + 1e-5f);
    __hip_bfloat16* op = out + (long)row * DD;
    op[tid]       = __float2bfloat16(d0 * rstd * g[tid]       + b[tid]);
    op[tid + 256] = __float2bfloat16(d1 * rstd * g[tid + 256] + b[tid + 256]);
    op[tid + 512] = __float2bfloat16(d2 * rstd * g[tid + 512] + b[tid + 512]);
}

// ---------------------------------------------------------------- embedding
__global__ void embed_kernel(const int* __restrict__ ids,
                             const float* __restrict__ tok,
                             const float* __restrict__ pos,
                             float* __restrict__ x)
{
    int row = blockIdx.x;             // 4096 = b*T + t
    int t = row & (TT - 1);
    long id = ids[row];
    int tid = threadIdx.x;
    float* xp = x + (long)row * DD;
    const float* tp = tok + id * DD;
    const float* pp = pos + (long)t * DD;
    for (int i = tid; i < DD; i += 256) xp[i] = tp[i] + pp[i];
}

// ------------------------------------------------------- causal softmax (S)
// one block (256 thr) per row of 1024; in-place bf16.
// Only cols < cmax = ((t>>7)+1)*128 are ever read downstream (PV K-trunc),
// so masked loads are skipped and stores stop at cmax.
__global__ void causal_softmax_kernel(__hip_bfloat16* __restrict__ S)
{
    long row = blockIdx.x;            // b*H*T + ... ; t = row % T
    int t = (int)(row & (TT - 1));
    int cmax = ((t >> 7) + 1) << 7;
    __hip_bfloat16* sp = S + row * TT;
    int tid = threadIdx.x;
    float v[4];
    float mx = -1e30f;
#pragma unroll
    for (int i = 0; i < 4; i++) {
        int c = tid + i * 256;
        float xv = -1e30f;
        if (c <= t) xv = __bfloat162float(sp[c]);
        v[i] = xv;
        mx = fmaxf(mx, xv);
    }
    for (int off = 32; off; off >>= 1) mx = fmaxf(mx, __shfl_down(mx, off));
    __shared__ float red[4];
    int wave = tid >> 6, lane = tid & 63;
    if (lane == 0) red[wave] = mx;
    __syncthreads();
    mx = fmaxf(fmaxf(red[0], red[1]), fmaxf(red[2], red[3]));
    float e[4];
    float sm = 0.f;
#pragma unroll
    for (int i = 0; i < 4; i++) {
        e[i] = (v[i] > -1e29f) ? __expf(v[i] - mx) : 0.f;
        sm += e[i];
    }
    for (int off = 32; off; off >>= 1) sm += __shfl_down(sm, off);
    __syncthreads();
    if (lane == 0) red[wave] = sm;
    __syncthreads();
    sm = red[0] + red[1] + red[2] + red[3];
    float inv = 1.f / sm;
#pragma unroll
    for (int i = 0; i < 4; i++) {
        int c = tid + i * 256;
        if (c < cmax) sp[c] = __float2bfloat16(e[i] * inv);
    }
}

// ---------------------------------------------------------------- loss
__global__ void row_loss_kernel(const float* __restrict__ logits,
                                const int* __restrict__ targets,
                                float* __restrict__ rowloss)
{
    int row = blockIdx.x;             // 4096
    const float* lp = logits + (long)row * NV;
    int tid = threadIdx.x;
    float mx = -1e30f, sm = 0.f;
    for (int i = tid; i < NV; i += 256) {
        float v = lp[i];
        if (v <= mx) sm += __expf(v - mx);
        else { sm = sm * __expf(mx - v) + 1.f; mx = v; }
    }
    for (int off = 32; off; off >>= 1) {
        float mo = __shfl_down(mx, off), so = __shfl_down(sm, off);
        float nm = fmaxf(mx, mo);
        sm = sm * __expf(mx - nm) + so * __expf(mo - nm);
        mx = nm;
    }
    __shared__ float smx[4], ssm[4];
    int wave = tid >> 6, lane = tid & 63;
    if (lane == 0) { smx[wave] = mx; ssm[wave] = sm; }
    __syncthreads();
    if (tid == 0) {
        float M = smx[0], Ssum = ssm[0];
        for (int w = 1; w < 4; w++) {
            float nm = fmaxf(M, smx[w]);
            Ssum = Ssum * __expf(M - nm) + ssm[w] * __expf(smx[w] - nm);
            M = nm;
        }
        float lse = M + logf(Ssum);
        rowloss[row] = lse - lp[targets[row]];
    }
}

__global__ void loss_reduce_kernel(const float* __restrict__ rowloss,
                                   float* __restrict__ out)
{
    int tid = threadIdx.x;
    float s = 0.f;
    for (int i = tid; i < BT; i += 256) s += rowloss[i];
    for (int off = 32; off; off >>= 1) s += __shfl_down(s, off);
    __shared__ float red[4];
    if ((tid & 63) == 0) red[tid >> 6] = s;
    __syncthreads();
    if (tid == 0) out[0] = (red[0] + red[1] + red[2] + red[3]) * (1.f / BT);
}

// ================================================================= launch
extern "C" void kernel_launch(void* const* d_in, const int* in_sizes, int n_in,
                              void* d_out, int out_size, void* d_ws, size_t ws_size,
                              hipStream_t stream)
{
    const int*   token_ids = (const int*)  d_in[0];
    const int*   targets   = (const int*)  d_in[1];
    const float* tok_emb   = (const float*)d_in[2];
    const float* pos_emb   = (const float*)d_in[3];
    const float* Wq        = (const float*)d_in[4];
    const float* Wk        = (const float*)d_in[5];
    const float* Wv        = (const float*)d_in[6];
    const float* Wproj     = (const float*)d_in[7];
    const float* bproj     = (const float*)d_in[8];
    const float* ln1_g     = (const float*)d_in[9];
    const float* ln1_b     = (const float*)d_in[10];
    const float* ln2_g     = (const float*)d_in[11];
    const float* ln2_b     = (const float*)d_in[12];
    const float* W1        = (const float*)d_in[13];
    const float* b1        = (const float*)d_in[14];
    const float* W2        = (const float*)d_in[15];
    const float* b2        = (const float*)d_in[16];
    const float* lnf_g     = (const float*)d_in[17];
    const float* lnf_b     = (const float*)d_in[18];
    const float* Whead     = (const float*)d_in[19];
    const float* bhead     = (const float*)d_in[20];

    float* logits   = (float*)d_out;
    float* loss_out = logits + (long)BT * NV;

    // ---- workspace carve-up (all rewritten every launch; ~332 MB total)
    char* ws = (char*)d_ws;
    size_t off = 0;
    auto alloc = [&](size_t bytes) {
        size_t p = off;
        off += (bytes + 255) & ~(size_t)255;
        return p;
    };
    float*          x    = (float*)         (ws + alloc((size_t)BT * DD * 4));
    __hip_bfloat16* h    = (__hip_bfloat16*)(ws + alloc((size_t)BT * DD * 2));
    __hip_bfloat16* qb   = (__hip_bfloat16*)(ws + alloc((size_t)BT * DD * 2));
    __hip_bfloat16* kb   = (__hip_bfloat16*)(ws + alloc((size_t)BT * DD * 2));
    __hip_bfloat16* vT   = (__hip_bfloat16*)(ws + alloc((size_t)NBATCH * NH * DD * TT * 2));
    __hip_bfloat16* Sb   = (__hip_bfloat16*)(ws + alloc((size_t)NBATCH * NH * TT * TT * 2));
    __hip_bfloat16* ob   = (__hip_bfloat16*)(ws + alloc((size_t)BT * HD * 2));
    __hip_bfloat16* wT   = (__hip_bfloat16*)(ws + alloc((size_t)NV * DD * 2)); // 49.15MB, >= per-layer 40.1MB
    float*          rowloss = (float*)      (ws + alloc((size_t)BT * 4));

    __hip_bfloat16* mid = Sb;   // alias: S dead during MLP, mid dead during attn

    __hip_bfloat16* wqT    = wT;
    __hip_bfloat16* wkT    = wqT + (long)DD * DD;
    __hip_bfloat16* wvT    = wkT + (long)DD * DD;
    __hip_bfloat16* wprojT = wvT + (long)NH * DD * DD;
    __hip_bfloat16* w1T    = wprojT + (long)DD * HD;
    __hip_bfloat16* w2T    = w1T + (long)FF * DD;
    __hip_bfloat16* wheadT = wT;   // reused after all layers

    dim3 tb(32, 8);

    embed_kernel<<<BT, 256, 0, stream>>>(token_ids, tok_emb, pos_emb, x);

    for (int l = 0; l < NL; l++) {
        // --- transpose this layer's weights to (N x K) bf16
        transpose_kernel<<<dim3(HK / 32, DD / 32, NH), tb, 0, stream>>>(
            Wq + (long)l * NH * DD * HK, wqT, DD, HK, (long)DD * HK, (long)HK * DD);
        transpose_kernel<<<dim3(HK / 32, DD / 32, NH), tb, 0, stream>>>(
            Wk + (long)l * NH * DD * HK, wkT, DD, HK, (long)DD * HK, (long)HK * DD);
        transpose_kernel<<<dim3(DD / 32, DD / 32, NH), tb, 0, stream>>>(
            Wv + (long)l * NH * DD * DD, wvT, DD, DD, (long)DD * DD, (long)DD * DD);
        transpose_kernel<<<dim3(DD / 32, HD / 32, 1), tb, 0, stream>>>(
            Wproj + (long)l * HD * DD, wprojT, HD, DD, 0, 0);
        transpose_kernel<<<dim3(FF / 32, DD / 32, 1), tb, 0, stream>>>(
            W1 + (long)l * DD * FF, w1T, DD, FF, 0, 0);
        transpose_kernel<<<dim3(DD / 32, FF / 32, 1), tb, 0, stream>>>(
            W2 + (long)l * FF * DD, w2T, FF, DD, 0, 0);

        // --- ln1
        ln_kernel<<<BT, 256, 0, stream>>>(x, ln1_g + l * DD, ln1_b + l * DD, h);

        // --- q, k: (BT x 768) = h @ WqT'   (cols = head*64+k)
        gemm_kernel<<<dim3(DD / 128, BT / 128, 1), 256, 0, stream>>>(
            h, wqT, qb, nullptr, DD, DD, DD, DD, 1, 0, 0, 0, 0, 0, 0,
            GF_OUTBF16, 1.0f);
        gemm_kernel<<<dim3(DD / 128, BT / 128, 1), 256, 0, stream>>>(
            h, wkT, kb, nullptr, DD, DD, DD, DD, 1, 0, 0, 0, 0, 0, 0,
            GF_OUTBF16, 1.0f);

        // --- vT[b,h,e,t] = sum_d Wv[h,d,e] * h[b,t,d]  (batch g = b*H + h)
        gemm_kernel<<<dim3(TT / 128, DD / 128, NBATCH * NH), 256, 0, stream>>>(
            wvT, h, vT, nullptr, DD, DD, DD, TT, NH,
            0, (long)DD * DD,                    // A = wvT + h*D*D
            (long)TT * DD, 0,                    // B = h + b*T*D
            (long)NH * DD * TT, (long)DD * TT,   // C = vT + g*D*T
            GF_OUTBF16, 1.0f);

        // --- S[b,h,t,s] = 0.125 * q . k   (batch g = b*H + h, K=64)
        //     tiles strictly above the diagonal are skipped (masked anyway)
        gemm_kernel<<<dim3(TT / 128, TT / 128, NBATCH * NH), 256, 0, stream>>>(
            qb, kb, Sb, nullptr, HK, DD, DD, TT, NH,
            (long)TT * DD, HK,                   // A = q + b*T*768 + h*64
            (long)TT * DD, HK,                   // B = k + b*T*768 + h*64
            (long)NH * TT * TT, (long)TT * TT,   // C = S + g*T*T
            GF_OUTBF16 | GF_CAUSAL, 0.125f);

        // --- causal softmax in-place
        causal_softmax_kernel<<<NBATCH * NH * TT, 256, 0, stream>>>(Sb);

        // --- o[b,t,h*768+e] = sum_s P[t,s] * vT[e,s]; P zero for s >= m0+128
        gemm_kernel<<<dim3(DD / 128, TT / 128, NBATCH * NH), 256, 0, stream>>>(
            Sb, vT, ob, nullptr, TT, TT, TT, HD, NH,
            (long)NH * TT * TT, (long)TT * TT,   // A = S + g*T*T
            (long)NH * DD * TT, (long)DD * TT,   // B = vT + g*D*T
            (long)TT * HD, DD,                   // C = o + b*T*9216 + h*768
            GF_OUTBF16 | GF_KTRUNC, 1.0f);

        // --- x += o @ Wproj + bproj
        gemm_kernel<<<dim3(DD / 128, BT / 128, 1), 256, 0, stream>>>(
            ob, wprojT, x, bproj + l * DD, HD, HD, HD, DD, 1,
            0, 0, 0, 0, 0, 0, GF_ACCUM | GF_BIAS, 1.0f);

        // --- ln2
        ln_kernel<<<BT, 256, 0, stream>>>(x, ln2_g + l * DD, ln2_b + l * DD, h);

        // --- mid = relu(h @ W1 + b1)
        gemm_kernel<<<dim3(FF / 128, BT / 128, 1), 256, 0, stream>>>(
            h, w1T, mid, b1 + (long)l * FF, DD, DD, DD, FF, 1,
            0, 0, 0, 0, 0, 0, GF_OUTBF16 | GF_BIAS | GF_RELU, 1.0f);

        // --- x += mid @ W2 + b2
        gemm_kernel<<<dim3(DD / 128, BT / 128, 1), 256, 0, stream>>>(
            mid, w2T, x, b2 + l * DD, FF, FF, FF, DD, 1,
            0, 0, 0, 0, 0, 0, GF_ACCUM | GF_BIAS, 1.0f);
    }

    // --- head
    transpose_kernel<<<dim3(NV / 32, DD / 32, 1), tb, 0, stream>>>(
        Whead, wheadT, DD, NV, 0, 0);
    ln_kernel<<<BT, 256, 0, stream>>>(x, lnf_g, lnf_b, h);
    gemm_kernel<<<dim3(NV / 128, BT / 128, 1), 256, 0, stream>>>(
        h, wheadT, logits, bhead, DD, DD, DD, NV, 1,
        0, 0, 0, 0, 0, 0, GF_BIAS | GF_SWIZZLE, 1.0f);

    // --- loss
    row_loss_kernel<<<BT, 256, 0, stream>>>(logits, targets, rowloss);
    loss_reduce_kernel<<<1, 256, 0, stream>>>(rowloss, loss_out);
}